// Round 10
// baseline (139.380 us; speedup 1.0000x reference)
//
#include <hip/hip_runtime.h>
#include <hip/hip_bf16.h>

#define B_ 4096
#define F_ 8
#define V_ 1000
#define D_ 1024
#define VP 1024

typedef __bf16 bf16x8 __attribute__((ext_vector_type(8)));
typedef float f32x4 __attribute__((ext_vector_type(4)));

__device__ __forceinline__ void gload_lds16(const void* g, void* l) {
  __builtin_amdgcn_global_load_lds(
      (const __attribute__((address_space(1))) void*)g,
      (__attribute__((address_space(3))) void*)l, 16, 0, 0);
}

// ---------------------------------------------------------------------------
// Kernel 0: W (F,D,V) f32 -> Wt (F, VP, D) bf16, zero-padded v in [V,VP)
// ---------------------------------------------------------------------------
__global__ __launch_bounds__(256) void transpose_w(
    const float* __restrict__ W, __hip_bfloat16* __restrict__ Wt) {
  __shared__ float tile[32][33];
  const int f = blockIdx.z;
  const int k0 = blockIdx.x * 32;
  const int v0 = blockIdx.y * 32;
  const int tx = threadIdx.x;
  const int ty = threadIdx.y;
  const float* Wf = W + (size_t)f * D_ * V_;
#pragma unroll
  for (int i = 0; i < 4; ++i) {
    int k = k0 + ty + i * 8;
    int v = v0 + tx;
    tile[ty + i * 8][tx] = (v < V_) ? Wf[k * V_ + v] : 0.0f;
  }
  __syncthreads();
  __hip_bfloat16* Wtf = Wt + (size_t)f * VP * D_;
#pragma unroll
  for (int i = 0; i < 4; ++i) {
    int v = v0 + ty + i * 8;
    int k = k0 + tx;
    Wtf[v * D_ + k] = __float2bfloat16(tile[tx][ty + i * 8]);
  }
}

// ---------------------------------------------------------------------------
// Kernel 1: fused gather + cumsum + LayerNorm + exact gelu -> H (F, B, D) bf16
// All 7 gathered rows prefetched upfront (independent loads in flight).
// ---------------------------------------------------------------------------
__global__ __launch_bounds__(256) void fuse_h(
    const float* __restrict__ emb, const int* __restrict__ feats,
    const float* __restrict__ tables, const float* __restrict__ gamma,
    const float* __restrict__ beta, __hip_bfloat16* __restrict__ H) {
  const int b = blockIdx.x;
  const int t = threadIdx.x;
  const int d = t * 4;
  const int wave = t >> 6, lane = t & 63;

  float s[4];
  {
    float4 v = *reinterpret_cast<const float4*>(&emb[(size_t)b * D_ + d]);
    s[0] = v.x; s[1] = v.y; s[2] = v.z; s[3] = v.w;
  }
  // prefetch all 7 gathered table rows (independent, latency overlapped)
  float4 tv[7];
#pragma unroll
  for (int j = 0; j < 7; ++j) {
    int feat = feats[b * F_ + j];
    tv[j] = *reinterpret_cast<const float4*>(
        &tables[((size_t)j * V_ + feat) * D_ + d]);
  }
  float gm[4], bt[4];
  {
    float4 g = *reinterpret_cast<const float4*>(&gamma[d]);
    float4 bb = *reinterpret_cast<const float4*>(&beta[d]);
    gm[0] = g.x; gm[1] = g.y; gm[2] = g.z; gm[3] = g.w;
    bt[0] = bb.x; bt[1] = bb.y; bt[2] = bb.z; bt[3] = bb.w;
  }
  __shared__ float red[2][4][2];

  for (int f = 0; f < F_; ++f) {
    float sum = s[0] + s[1] + s[2] + s[3];
    float ssq = s[0] * s[0] + s[1] * s[1] + s[2] * s[2] + s[3] * s[3];
#pragma unroll
    for (int off = 32; off > 0; off >>= 1) {
      sum += __shfl_xor(sum, off, 64);
      ssq += __shfl_xor(ssq, off, 64);
    }
    const int pb = f & 1;
    if (lane == 0) { red[pb][wave][0] = sum; red[pb][wave][1] = ssq; }
    __syncthreads();
    sum = red[pb][0][0] + red[pb][1][0] + red[pb][2][0] + red[pb][3][0];
    ssq = red[pb][0][1] + red[pb][1][1] + red[pb][2][1] + red[pb][3][1];

    const float mu = sum * (1.0f / D_);
    const float var = ssq * (1.0f / D_) - mu * mu;
    const float rstd = rsqrtf(var + 1e-5f);

    __hip_bfloat16 hb[4];
#pragma unroll
    for (int j = 0; j < 4; ++j) {
      float x = (s[j] - mu) * rstd * gm[j] + bt[j];
      float g = 0.5f * x * (1.0f + erff(x * 0.70710678118654752f));
      hb[j] = __float2bfloat16(g);
    }
    *reinterpret_cast<uint2*>(&H[(size_t)f * (B_ * D_) + (size_t)b * D_ + d]) =
        *reinterpret_cast<const uint2*>(hb);

    if (f < F_ - 1) {
      s[0] += tv[f].x; s[1] += tv[f].y; s[2] += tv[f].z; s[3] += tv[f].w;
    }
  }
}

// ---------------------------------------------------------------------------
// Kernel 2: 256x256 8-phase GEMM, BK=64, 8 waves (2Mx4N), dbuf LDS (4 separate
// __shared__ objects). Fragments ds_read ONE PHASE AHEAD of their MFMA; NO
// explicit lgkm drains -- the compiler inserts minimal COUNTED lgkmcnt(N)
// before each MFMA cluster (SB0 pins reads before MFMA). Explicit waits are
// only the staging certification: VM4 at PH4/PH8 (collective via barrier).
// ---------------------------------------------------------------------------
#define STAGE(ARR, GB, HALF, KT)                                              \
  do {                                                                        \
    const ushort* _g = (GB) + (size_t)(HALF) * (128 * D_) + (size_t)(KT) * 64;\
    ushort* _l = &ARR[(HALF)*8192 + w * 512];                                 \
    gload_lds16(_g, _l);                                                      \
    gload_lds16(_g + 64 * D_, _l + 4096);                                     \
  } while (0)

#define LD_A(DST, LBASE, FIOFF)                                               \
  _Pragma("unroll") for (int _fj = 0; _fj < 4; ++_fj)                         \
  _Pragma("unroll") for (int _ks = 0; _ks < 2; ++_ks)                         \
      DST[_fj][_ks] = *reinterpret_cast<const bf16x8*>(                       \
          (LBASE) + ((((FIOFF) + _fj) * 2 + _ks) * 512));

#define LD_B(DST, LBASE, NFOFF)                                               \
  _Pragma("unroll") for (int _fn = 0; _fn < 2; ++_fn)                         \
  _Pragma("unroll") for (int _ks = 0; _ks < 2; ++_ks)                         \
      DST[_fn][_ks] = *reinterpret_cast<const bf16x8*>(                       \
          (LBASE) + ((((NFOFF) + _fn) * 2 + _ks) * 512));

#define Q_MFMA(AF, BF, R0, C0)                                                \
  do {                                                                        \
    __builtin_amdgcn_s_setprio(1);                                            \
    _Pragma("unroll") for (int _fj = 0; _fj < 4; ++_fj)                       \
    _Pragma("unroll") for (int _fn = 0; _fn < 2; ++_fn)                       \
    _Pragma("unroll") for (int _ks = 0; _ks < 2; ++_ks)                       \
        acc[(R0) + _fj][(C0) + _fn] =                                         \
            __builtin_amdgcn_mfma_f32_16x16x32_bf16(                          \
                AF[_fj][_ks], BF[_fn][_ks], acc[(R0) + _fj][(C0) + _fn],      \
                0, 0, 0);                                                     \
    __builtin_amdgcn_s_setprio(0);                                            \
  } while (0)

#define BAR __builtin_amdgcn_s_barrier()
#define SB0 __builtin_amdgcn_sched_barrier(0)
#define VM4 asm volatile("s_waitcnt vmcnt(4)")
#define VM0 asm volatile("s_waitcnt vmcnt(0)")

__global__ __launch_bounds__(512, 2) void gemm_hw(
    const ushort* __restrict__ H,    // (F, B, D) bf16
    const ushort* __restrict__ Wt,   // (F, VP, D) bf16
    const float* __restrict__ bias,  // (F, V)
    float* __restrict__ out) {       // (B, F, V)
  __shared__ ushort Ad0[16384];  // 32 KB: A dbuf0
  __shared__ ushort Ad1[16384];  // 32 KB: A dbuf1
  __shared__ ushort Bd0[16384];  // 32 KB: B dbuf0
  __shared__ ushort Bd1[16384];  // 32 KB: B dbuf1

  // bijective XCD swizzle: nwg=512, 512%8==0
  const int bid = blockIdx.x;
  const int swz = (bid & 7) * 64 + (bid >> 3);
  const int f = swz >> 6;
  const int r = swz & 63;
  const int mt = r >> 2, nt = r & 3;

  const int t = threadIdx.x;
  const int w = t >> 6, l = t & 63;
  const int wm = w >> 2;   // 0..1 (M)
  const int wn = w & 3;    // 0..3 (N)

  const ushort* Hf = H + (size_t)f * (B_ * D_);
  const ushort* Wf = Wt + (size_t)f * (VP * D_);

  // staging global source (pre-swizzled so linear LDS write = swizzled layout)
  const int srow = ((w >> 1) << 4) + (l >> 2);
  const int skx = ((w & 1) << 5) + ((((l & 3) << 3)) ^ (((l >> 5) & 1) << 4));
  const ushort* gA = Hf + (size_t)(mt * 256 + srow) * D_ + skx;
  const ushort* gB = Wf + (size_t)(nt * 256 + srow) * D_ + skx;

  // ds_read per-lane offset (ushorts): same swizzle on read side
  const int laneu =
      ((l & 15) << 5) + (((((l >> 4) << 4)) ^ (((l >> 3) & 1) << 5)) >> 1);
  const ushort* lA[2] = {&Ad0[wm * 8192 + laneu], &Ad1[wm * 8192 + laneu]};
  const ushort* lB[2] = {&Bd0[(wn >> 1) * 8192 + (wn & 1) * 4096 + laneu],
                         &Bd1[(wn >> 1) * 8192 + (wn & 1) * 4096 + laneu]};

  bf16x8 a0[4][2], a1[4][2], b0[2][2], b1[2][2];
  f32x4 acc[8][4] = {};

  // prologue: d0{A0,A1,B0,B1}(T0) then d1{A0,A1}(T1) -> 12 vm-ops.
  // VM4 drains the 8 T0 ops, leaves the 4 d1.A(T1) in flight.
  STAGE(Ad0, gA, 0, 0);
  STAGE(Ad0, gA, 1, 0);
  STAGE(Bd0, gB, 0, 0);
  STAGE(Bd0, gB, 1, 0);
  STAGE(Ad1, gA, 0, 1);
  STAGE(Ad1, gA, 1, 1);
  VM4;
  BAR;
  // pre-reads for PH1's MFMA: a0 <- d0.A-lo, b0 <- d0.B-lo
  LD_A(a0, lA[0], 0);
  LD_B(b0, lB[0], 0);
  SB0;

#pragma unroll 1
  for (int i = 0; i < 8; ++i) {
    const int t1 = 2 * i + 1, t2 = 2 * i + 2, t3 = 2 * i + 3;
    const bool more = (i < 7);
    // PH1: stage d1.B0(T1); read a1<-d0.A-hi; MFMA a0*b0
    STAGE(Bd1, gB, 0, t1);
    BAR;
    SB0;
    LD_A(a1, lA[0], 4);
    SB0;
    Q_MFMA(a0, b0, 0, 0);
    // PH2: stage d1.B1(T1); read b1<-d0.B-hi; MFMA a1*b0
    STAGE(Bd1, gB, 1, t1);
    BAR;
    SB0;
    LD_B(b1, lB[0], 2);
    SB0;
    Q_MFMA(a1, b0, 4, 0);
    // PH3: stage d0.A0(T2); MFMA a0*b1
    if (more) STAGE(Ad0, gA, 0, t2);
    BAR;
    SB0;
    Q_MFMA(a0, b1, 0, 2);
    // PH4: stage d0.A1(T2); VM4 certifies all of d1(T1); read a0,b0 <- d1
    if (more) {
      STAGE(Ad0, gA, 1, t2);
      VM4;
    } else {
      VM0;
    }
    BAR;
    SB0;
    LD_A(a0, lA[1], 0);
    LD_B(b0, lB[1], 0);
    SB0;
    Q_MFMA(a1, b1, 4, 2);
    // PH5: stage d0.B0(T2); read a1<-d1.A-hi; MFMA a0*b0 (T1)
    if (more) STAGE(Bd0, gB, 0, t2);
    BAR;
    SB0;
    LD_A(a1, lA[1], 4);
    SB0;
    Q_MFMA(a0, b0, 0, 0);
    // PH6: stage d0.B1(T2); read b1<-d1.B-hi; MFMA a1*b0 (T1)
    if (more) STAGE(Bd0, gB, 1, t2);
    BAR;
    SB0;
    LD_B(b1, lB[1], 2);
    SB0;
    Q_MFMA(a1, b0, 4, 0);
    // PH7: stage d1.A0(T3); MFMA a0*b1 (T1)
    if (more) STAGE(Ad1, gA, 0, t3);
    BAR;
    SB0;
    Q_MFMA(a0, b1, 0, 2);
    // PH8: stage d1.A1(T3); VM4 certifies all of d0(T2); read a0,b0 <- d0
    if (more) {
      STAGE(Ad1, gA, 1, t3);
      VM4;
    }
    BAR;
    SB0;
    if (more) {
      LD_A(a0, lA[0], 0);
      LD_B(b0, lB[0], 0);
    }
    SB0;
    Q_MFMA(a1, b1, 4, 2);
  }

  // epilogue: C layout col = lane&15, row = (lane>>4)*4 + q
  const float* bp = bias + f * V_;
  const int orow0 = mt * 256 + wm * 128 + ((l >> 4) << 2);
  const int ocol0 = nt * 256 + wn * 64 + (l & 15);
#pragma unroll
  for (int fi = 0; fi < 8; ++fi) {
#pragma unroll
    for (int fn = 0; fn < 4; ++fn) {
      int col = ocol0 + fn * 16;
      if (col < V_) {
        float bb = bp[col];
        int row = orow0 + fi * 16;
        float* op = out + (size_t)row * (F_ * V_) + (size_t)f * V_ + col;
#pragma unroll
        for (int q = 0; q < 4; ++q)
          op[(size_t)q * (F_ * V_)] = acc[fi][fn][q] + bb;
      }
    }
  }
}

// ---------------------------------------------------------------------------
extern "C" void kernel_launch(void* const* d_in, const int* in_sizes, int n_in,
                              void* d_out, int out_size, void* d_ws,
                              size_t ws_size, hipStream_t stream) {
  const float* emb = (const float*)d_in[0];     // (B, D)
  const int* feats = (const int*)d_in[1];       // (B, F)
  const float* tables = (const float*)d_in[2];  // (F, V, D)
  const float* gamma = (const float*)d_in[3];   // (D,)
  const float* beta = (const float*)d_in[4];    // (D,)
  const float* W = (const float*)d_in[5];       // (F, D, V)
  const float* bias = (const float*)d_in[6];    // (F, V)
  float* out = (float*)d_out;                   // (B, F, V)

  char* ws = (char*)d_ws;
  __hip_bfloat16* Hbuf = (__hip_bfloat16*)ws;  // F*B*D*2 = 64 MiB
  __hip_bfloat16* Wtbuf =
      (__hip_bfloat16*)(ws + (size_t)F_ * B_ * D_ * 2);  // F*VP*D*2 = 16 MiB

  transpose_w<<<dim3(D_ / 32, VP / 32, F_), dim3(32, 8), 0, stream>>>(W, Wtbuf);
  fuse_h<<<dim3(B_), dim3(256), 0, stream>>>(emb, feats, tables, gamma, beta,
                                             Hbuf);
  gemm_hw<<<dim3((B_ / 256) * (VP / 256) * F_), dim3(512), 0, stream>>>(
      (const ushort*)Hbuf, (const ushort*)Wtbuf, bias, out);
}

// Round 12
// 130.360 us; speedup vs baseline: 1.0692x; 1.0692x over previous
//
#include <hip/hip_runtime.h>
#include <hip/hip_bf16.h>

#define B_ 4096
#define F_ 8
#define V_ 1000
#define D_ 1024
#define VP 1024

typedef __bf16 bf16x8 __attribute__((ext_vector_type(8)));
typedef float f32x4 __attribute__((ext_vector_type(4)));

__device__ __forceinline__ void gload_lds16(const void* g, void* l) {
  __builtin_amdgcn_global_load_lds(
      (const __attribute__((address_space(1))) void*)g,
      (__attribute__((address_space(3))) void*)l, 16, 0, 0);
}

// ---------------------------------------------------------------------------
// Kernel 0: W (F,D,V) f32 -> Wt (F, VP, D) bf16, zero-padded v in [V,VP)
// 64x64 tiles, 256 threads, float4 loads, 8B packed bf16 stores.
// ---------------------------------------------------------------------------
__global__ __launch_bounds__(256) void transpose_w(
    const float* __restrict__ W, __hip_bfloat16* __restrict__ Wt) {
  __shared__ float tile[64][65];
  const int id = blockIdx.x;            // 2048 = 8 f x 16 v x 16 k
  const int f = id >> 8;
  const int v0 = ((id >> 4) & 15) * 64;
  const int k0 = (id & 15) * 64;
  const int t = threadIdx.x;
  const int tx = t & 15;   // float4 col within 64
  const int ty = t >> 4;   // 16 rows per pass
  const float* Wf = W + (size_t)f * D_ * V_;
#pragma unroll
  for (int p = 0; p < 4; ++p) {
    int k = k0 + ty + p * 16;
    int v = v0 + tx * 4;
    float4 val;
    if (v + 3 < V_) {
      val = *reinterpret_cast<const float4*>(&Wf[(size_t)k * V_ + v]);
    } else {
      val.x = (v + 0 < V_) ? Wf[(size_t)k * V_ + v + 0] : 0.0f;
      val.y = (v + 1 < V_) ? Wf[(size_t)k * V_ + v + 1] : 0.0f;
      val.z = (v + 2 < V_) ? Wf[(size_t)k * V_ + v + 2] : 0.0f;
      val.w = (v + 3 < V_) ? Wf[(size_t)k * V_ + v + 3] : 0.0f;
    }
    tile[ty + p * 16][tx * 4 + 0] = val.x;
    tile[ty + p * 16][tx * 4 + 1] = val.y;
    tile[ty + p * 16][tx * 4 + 2] = val.z;
    tile[ty + p * 16][tx * 4 + 3] = val.w;
  }
  __syncthreads();
  __hip_bfloat16* Wtf = Wt + (size_t)f * VP * D_;
#pragma unroll
  for (int p = 0; p < 4; ++p) {
    int vr = ty + p * 16;          // row of Wt within tile
    int kc = tx * 4;               // col (k) within tile
    __hip_bfloat16 hb[4];
#pragma unroll
    for (int j = 0; j < 4; ++j)
      hb[j] = __float2bfloat16(tile[kc + j][vr]);
    *reinterpret_cast<uint2*>(&Wtf[(size_t)(v0 + vr) * D_ + k0 + kc]) =
        *reinterpret_cast<const uint2*>(hb);
  }
}

// ---------------------------------------------------------------------------
// Kernel 1: fused gather + cumsum + LayerNorm + exact gelu -> H (F, B, D) bf16
// ONE WAVE PER ROW: lane owns 16 floats (4x float4, coalesced), reductions
// via 6-level shfl_xor (no LDS, no barriers). Gather rows double-buffered.
// ---------------------------------------------------------------------------
__global__ __launch_bounds__(256) void fuse_h(
    const float* __restrict__ emb, const int* __restrict__ feats,
    const float* __restrict__ tables, const float* __restrict__ gamma,
    const float* __restrict__ beta, __hip_bfloat16* __restrict__ H) {
  const int t = threadIdx.x;
  const int wave = t >> 6, lane = t & 63;
  const int b = blockIdx.x * 4 + wave;  // grid 1024 x 4 waves

  // lane owns d = lane*4 + j*256, j = 0..3 (4 float4 chunks, coalesced)
  float s[16];
#pragma unroll
  for (int j = 0; j < 4; ++j) {
    float4 v = *reinterpret_cast<const float4*>(
        &emb[(size_t)b * D_ + lane * 4 + j * 256]);
    s[j * 4 + 0] = v.x; s[j * 4 + 1] = v.y;
    s[j * 4 + 2] = v.z; s[j * 4 + 3] = v.w;
  }
  float gm[16], bt[16];
#pragma unroll
  for (int j = 0; j < 4; ++j) {
    float4 g = *reinterpret_cast<const float4*>(&gamma[lane * 4 + j * 256]);
    float4 bb = *reinterpret_cast<const float4*>(&beta[lane * 4 + j * 256]);
    gm[j * 4 + 0] = g.x; gm[j * 4 + 1] = g.y;
    gm[j * 4 + 2] = g.z; gm[j * 4 + 3] = g.w;
    bt[j * 4 + 0] = bb.x; bt[j * 4 + 1] = bb.y;
    bt[j * 4 + 2] = bb.z; bt[j * 4 + 3] = bb.w;
  }

  // double-buffered gather: nxt holds row f's embedding (used at end of iter f)
  float4 nxt[4];
  {
    int feat = feats[b * F_ + 0];
    const float* row = tables + ((size_t)0 * V_ + feat) * D_;
#pragma unroll
    for (int j = 0; j < 4; ++j)
      nxt[j] = *reinterpret_cast<const float4*>(&row[lane * 4 + j * 256]);
  }

  for (int f = 0; f < F_; ++f) {
    float sum = 0.0f, ssq = 0.0f;
#pragma unroll
    for (int j = 0; j < 16; ++j) {
      sum += s[j];
      ssq += s[j] * s[j];
    }
#pragma unroll
    for (int off = 32; off > 0; off >>= 1) {
      sum += __shfl_xor(sum, off, 64);
      ssq += __shfl_xor(ssq, off, 64);
    }
    const float mu = sum * (1.0f / D_);
    const float var = ssq * (1.0f / D_) - mu * mu;
    const float rstd = rsqrtf(var + 1e-5f);

    __hip_bfloat16* Hrow = H + (size_t)f * (B_ * D_) + (size_t)b * D_;
#pragma unroll
    for (int j = 0; j < 4; ++j) {
      __hip_bfloat16 hb[4];
#pragma unroll
      for (int q = 0; q < 4; ++q) {
        float x = (s[j * 4 + q] - mu) * rstd * gm[j * 4 + q] + bt[j * 4 + q];
        float g = 0.5f * x * (1.0f + erff(x * 0.70710678118654752f));
        hb[q] = __float2bfloat16(g);
      }
      *reinterpret_cast<uint2*>(&Hrow[lane * 4 + j * 256]) =
          *reinterpret_cast<const uint2*>(hb);
    }

    if (f < F_ - 1) {
      // consume nxt (row f), then prefetch row f+1
      float4 cur[4];
#pragma unroll
      for (int j = 0; j < 4; ++j) cur[j] = nxt[j];
      if (f < F_ - 2) {
        int feat = feats[b * F_ + f + 1];
        const float* row = tables + ((size_t)(f + 1) * V_ + feat) * D_;
#pragma unroll
        for (int j = 0; j < 4; ++j)
          nxt[j] = *reinterpret_cast<const float4*>(&row[lane * 4 + j * 256]);
      }
#pragma unroll
      for (int j = 0; j < 4; ++j) {
        s[j * 4 + 0] += cur[j].x; s[j * 4 + 1] += cur[j].y;
        s[j * 4 + 2] += cur[j].z; s[j * 4 + 3] += cur[j].w;
      }
    }
  }
}

// ---------------------------------------------------------------------------
// Kernel 2: 256x256 8-phase GEMM (R3-exact, best measured 82.6 us), BK=64,
// 8 waves (2Mx4N), dbuf LDS, pre-swizzled global source, one raw s_barrier
// per phase, counted vmcnt(6) at PH4/PH8 only.
// ---------------------------------------------------------------------------
#define AOFF 0
#define BOFF 32768

#define STAGE(OPB, GB, DBUF, HALF, KT)                                        \
  do {                                                                        \
    const ushort* _g = (GB) + (size_t)(HALF) * (128 * D_) + (size_t)(KT) * 64;\
    ushort* _l = &lds[(OPB) + ((DBUF)*2 + (HALF)) * 8192 + w * 512];          \
    gload_lds16(_g, _l);                                                      \
    gload_lds16(_g + 64 * D_, _l + 4096);                                     \
  } while (0)

#define LD_A(DST, LBASE, FIOFF)                                               \
  _Pragma("unroll") for (int _fj = 0; _fj < 4; ++_fj)                         \
  _Pragma("unroll") for (int _ks = 0; _ks < 2; ++_ks)                         \
      DST[_fj][_ks] = *reinterpret_cast<const bf16x8*>(                       \
          (LBASE) + ((((FIOFF) + _fj) * 2 + _ks) * 512));

#define LD_B(DST, LBASE, NFOFF)                                               \
  _Pragma("unroll") for (int _fn = 0; _fn < 2; ++_fn)                         \
  _Pragma("unroll") for (int _ks = 0; _ks < 2; ++_ks)                         \
      DST[_fn][_ks] = *reinterpret_cast<const bf16x8*>(                       \
          (LBASE) + ((((NFOFF) + _fn) * 2 + _ks) * 512));

#define Q_MFMA(AF, BF, R0, C0)                                                \
  do {                                                                        \
    __builtin_amdgcn_s_setprio(1);                                            \
    _Pragma("unroll") for (int _fj = 0; _fj < 4; ++_fj)                       \
    _Pragma("unroll") for (int _fn = 0; _fn < 2; ++_fn)                       \
    _Pragma("unroll") for (int _ks = 0; _ks < 2; ++_ks)                       \
        acc[(R0) + _fj][(C0) + _fn] =                                         \
            __builtin_amdgcn_mfma_f32_16x16x32_bf16(                          \
                AF[_fj][_ks], BF[_fn][_ks], acc[(R0) + _fj][(C0) + _fn],      \
                0, 0, 0);                                                     \
    __builtin_amdgcn_s_setprio(0);                                            \
  } while (0)

#define PHB                                                                   \
  do {                                                                        \
    asm volatile("" ::: "memory");                                            \
    __builtin_amdgcn_s_barrier();                                             \
    asm volatile("" ::: "memory");                                            \
  } while (0)

#define WAITV6 asm volatile("s_waitcnt vmcnt(6)" ::: "memory")
#define WAITV0 asm volatile("s_waitcnt vmcnt(0)" ::: "memory")

__global__ __launch_bounds__(512, 2) void gemm_hw(
    const ushort* __restrict__ H,    // (F, B, D) bf16
    const ushort* __restrict__ Wt,   // (F, VP, D) bf16
    const float* __restrict__ bias,  // (F, V)
    float* __restrict__ out) {       // (B, F, V)
  __shared__ ushort lds[65536];  // 128 KiB

  // bijective XCD swizzle: nwg=512, 512%8==0
  const int bid = blockIdx.x;
  const int swz = (bid & 7) * 64 + (bid >> 3);
  const int f = swz >> 6;
  const int r = swz & 63;
  const int mt = r >> 2, nt = r & 3;

  const int t = threadIdx.x;
  const int w = t >> 6, l = t & 63;
  const int wm = w >> 2;   // 0..1 (M)
  const int wn = w & 3;    // 0..3 (N)

  const ushort* Hf = H + (size_t)f * (B_ * D_);
  const ushort* Wf = Wt + (size_t)f * (VP * D_);

  // staging global source (pre-swizzled so linear LDS write = swizzled layout)
  const int srow = ((w >> 1) << 4) + (l >> 2);
  const int skx = ((w & 1) << 5) + ((((l & 3) << 3)) ^ (((l >> 5) & 1) << 4));
  const ushort* gA = Hf + (size_t)(mt * 256 + srow) * D_ + skx;
  const ushort* gB = Wf + (size_t)(nt * 256 + srow) * D_ + skx;

  // ds_read per-lane offset (ushorts): same swizzle on read side
  const int laneu =
      ((l & 15) << 5) + (((((l >> 4) << 4)) ^ (((l >> 3) & 1) << 5)) >> 1);
  const ushort* lA[2] = {&lds[(0 * 2 + wm) * 8192 + laneu],
                         &lds[(1 * 2 + wm) * 8192 + laneu]};
  const ushort* lB[2] = {
      &lds[BOFF + (0 * 2 + (wn >> 1)) * 8192 + (wn & 1) * 4096 + laneu],
      &lds[BOFF + (1 * 2 + (wn >> 1)) * 8192 + (wn & 1) * 4096 + laneu]};

  bf16x8 a0[4][2], a1[4][2], b0[2][2], b1[2][2];
  f32x4 acc[8][4] = {};

  // prologue: T0 full + T1 {A0,A1,B0}; B1(T1) staged at PH1 of iter 0.
  STAGE(AOFF, gA, 0, 0, 0);
  STAGE(AOFF, gA, 0, 1, 0);
  STAGE(BOFF, gB, 0, 0, 0);
  STAGE(BOFF, gB, 0, 1, 0);
  STAGE(AOFF, gA, 1, 0, 1);
  STAGE(AOFF, gA, 1, 1, 1);
  STAGE(BOFF, gB, 1, 0, 1);
  WAITV6;  // 14 issued, keep 6 -> drains exactly T0's 8 loads
  PHB;

#pragma unroll 1
  for (int i = 0; i < 8; ++i) {
    const int t1 = 2 * i + 1, t2 = 2 * i + 2, t3 = 2 * i + 3;
    const bool more = (i < 7);
    // ---- PH1: read a0,b0(T0); stage B1(T1)
    LD_A(a0, lA[0], 0);
    LD_B(b0, lB[0], 0);
    STAGE(BOFF, gB, 1, 1, t1);
    PHB;
    Q_MFMA(a0, b0, 0, 0);
    // ---- PH2: read a1(T0); stage A0(T2)
    LD_A(a1, lA[0], 4);
    if (more) STAGE(AOFF, gA, 0, 0, t2);
    PHB;
    Q_MFMA(a1, b0, 4, 0);
    // ---- PH3: read b1(T0); stage A1(T2)
    LD_B(b1, lB[0], 2);
    if (more) STAGE(AOFF, gA, 0, 1, t2);
    PHB;
    Q_MFMA(a0, b1, 0, 2);
    // ---- PH4: stage B0(T2); counted wait (T1 fully landed)
    if (more) STAGE(BOFF, gB, 0, 0, t2);
    if (more) { WAITV6; } else { WAITV0; }
    PHB;
    Q_MFMA(a1, b1, 4, 2);
    // ---- PH5: read a0,b0(T1); stage B1(T2)
    LD_A(a0, lA[1], 0);
    LD_B(b0, lB[1], 0);
    if (more) STAGE(BOFF, gB, 0, 1, t2);
    PHB;
    Q_MFMA(a0, b0, 0, 0);
    // ---- PH6: read a1(T1); stage A0(T3)
    LD_A(a1, lA[1], 4);
    if (more) STAGE(AOFF, gA, 1, 0, t3);
    PHB;
    Q_MFMA(a1, b0, 4, 0);
    // ---- PH7: read b1(T1); stage A1(T3)
    LD_B(b1, lB[1], 2);
    if (more) STAGE(AOFF, gA, 1, 1, t3);
    PHB;
    Q_MFMA(a0, b1, 0, 2);
    // ---- PH8: stage B0(T3); counted wait (T2 fully landed)
    if (more) {
      STAGE(BOFF, gB, 1, 0, t3);
      WAITV6;
    }
    PHB;
    Q_MFMA(a1, b1, 4, 2);
  }

  // epilogue: C layout col = lane&15, row = (lane>>4)*4 + q
  const float* bp = bias + f * V_;
  const int orow0 = mt * 256 + wm * 128 + ((l >> 4) << 2);
  const int ocol0 = nt * 256 + wn * 64 + (l & 15);
#pragma unroll
  for (int fi = 0; fi < 8; ++fi) {
#pragma unroll
    for (int fn = 0; fn < 4; ++fn) {
      int col = ocol0 + fn * 16;
      if (col < V_) {
        float bb = bp[col];
        int row = orow0 + fi * 16;
        float* op = out + (size_t)row * (F_ * V_) + (size_t)f * V_ + col;
#pragma unroll
        for (int q = 0; q < 4; ++q)
          op[(size_t)q * (F_ * V_)] = acc[fi][fn][q] + bb;
      }
    }
  }
}

// ---------------------------------------------------------------------------
extern "C" void kernel_launch(void* const* d_in, const int* in_sizes, int n_in,
                              void* d_out, int out_size, void* d_ws,
                              size_t ws_size, hipStream_t stream) {
  const float* emb = (const float*)d_in[0];     // (B, D)
  const int* feats = (const int*)d_in[1];       // (B, F)
  const float* tables = (const float*)d_in[2];  // (F, V, D)
  const float* gamma = (const float*)d_in[3];   // (D,)
  const float* beta = (const float*)d_in[4];    // (D,)
  const float* W = (const float*)d_in[5];       // (F, D, V)
  const float* bias = (const float*)d_in[6];    // (F, V)
  float* out = (float*)d_out;                   // (B, F, V)

  char* ws = (char*)d_ws;
  __hip_bfloat16* Hbuf = (__hip_bfloat16*)ws;  // F*B*D*2 = 64 MiB
  __hip_bfloat16* Wtbuf =
      (__hip_bfloat16*)(ws + (size_t)F_ * B_ * D_ * 2);  // F*VP*D*2 = 16 MiB

  transpose_w<<<dim3(2048), dim3(256), 0, stream>>>(W, Wtbuf);
  fuse_h<<<dim3(1024), dim3(256), 0, stream>>>(emb, feats, tables, gamma,
                                               beta, Hbuf);
  gemm_hw<<<dim3((B_ / 256) * (VP / 256) * F_), dim3(512), 0, stream>>>(
      (const ushort*)Hbuf, (const ushort*)Wtbuf, bias, out);
}

// Round 13
// 128.156 us; speedup vs baseline: 1.0876x; 1.0172x over previous
//
#include <hip/hip_runtime.h>
#include <hip/hip_bf16.h>

#define B_ 4096
#define F_ 8
#define V_ 1000
#define D_ 1024
#define VP 1024

typedef __bf16 bf16x8 __attribute__((ext_vector_type(8)));
typedef float f32x4 __attribute__((ext_vector_type(4)));

__device__ __forceinline__ void gload_lds16(const void* g, void* l) {
  __builtin_amdgcn_global_load_lds(
      (const __attribute__((address_space(1))) void*)g,
      (__attribute__((address_space(3))) void*)l, 16, 0, 0);
}

// fast gelu: tanh form, z clamped so exp never overflows.
// max abs err vs exact erf-gelu ~3e-4 (negligible vs 4.4e-2 threshold).
__device__ __forceinline__ float gelu_fast(float x) {
  float z = 0.7978845608028654f * (x + 0.044715f * x * x * x);
  z = fminf(fmaxf(z, -9.0f), 9.0f);
  float e = __expf(2.0f * z);
  float t = (e - 1.0f) / (e + 1.0f);
  return 0.5f * x * (1.0f + t);
}

// ---------------------------------------------------------------------------
// Kernel 0: W (F,D,V) f32 -> Wt (F, VP, D) bf16, zero-padded v in [V,VP)
// 64x64 tiles, 256 threads, float4 loads, 8B packed bf16 stores.
// ---------------------------------------------------------------------------
__global__ __launch_bounds__(256) void transpose_w(
    const float* __restrict__ W, __hip_bfloat16* __restrict__ Wt) {
  __shared__ float tile[64][65];
  const int id = blockIdx.x;            // 2048 = 8 f x 16 v x 16 k
  const int f = id >> 8;
  const int v0 = ((id >> 4) & 15) * 64;
  const int k0 = (id & 15) * 64;
  const int t = threadIdx.x;
  const int tx = t & 15;   // float4 col within 64
  const int ty = t >> 4;   // 16 rows per pass
  const float* Wf = W + (size_t)f * D_ * V_;
#pragma unroll
  for (int p = 0; p < 4; ++p) {
    int k = k0 + ty + p * 16;
    int v = v0 + tx * 4;
    float4 val;
    if (v + 3 < V_) {
      val = *reinterpret_cast<const float4*>(&Wf[(size_t)k * V_ + v]);
    } else {
      val.x = (v + 0 < V_) ? Wf[(size_t)k * V_ + v + 0] : 0.0f;
      val.y = (v + 1 < V_) ? Wf[(size_t)k * V_ + v + 1] : 0.0f;
      val.z = (v + 2 < V_) ? Wf[(size_t)k * V_ + v + 2] : 0.0f;
      val.w = (v + 3 < V_) ? Wf[(size_t)k * V_ + v + 3] : 0.0f;
    }
    tile[ty + p * 16][tx * 4 + 0] = val.x;
    tile[ty + p * 16][tx * 4 + 1] = val.y;
    tile[ty + p * 16][tx * 4 + 2] = val.z;
    tile[ty + p * 16][tx * 4 + 3] = val.w;
  }
  __syncthreads();
  __hip_bfloat16* Wtf = Wt + (size_t)f * VP * D_;
#pragma unroll
  for (int p = 0; p < 4; ++p) {
    int vr = ty + p * 16;          // row of Wt within tile
    int kc = tx * 4;               // col (k) within tile
    __hip_bfloat16 hb[4];
#pragma unroll
    for (int j = 0; j < 4; ++j)
      hb[j] = __float2bfloat16(tile[kc + j][vr]);
    *reinterpret_cast<uint2*>(&Wtf[(size_t)(v0 + vr) * D_ + k0 + kc]) =
        *reinterpret_cast<const uint2*>(hb);
  }
}

// ---------------------------------------------------------------------------
// Kernel 1: fused gather + cumsum + LayerNorm + fast gelu -> H (F, B, D) bf16
// ONE WAVE PER ROW: lane owns 16 floats (4x float4, coalesced), reductions
// via 6-level shfl_xor (no LDS, no barriers). Gather rows double-buffered.
// ---------------------------------------------------------------------------
__global__ __launch_bounds__(256) void fuse_h(
    const float* __restrict__ emb, const int* __restrict__ feats,
    const float* __restrict__ tables, const float* __restrict__ gamma,
    const float* __restrict__ beta, __hip_bfloat16* __restrict__ H) {
  const int t = threadIdx.x;
  const int wave = t >> 6, lane = t & 63;
  const int b = blockIdx.x * 4 + wave;  // grid 1024 x 4 waves

  // lane owns d = lane*4 + j*256, j = 0..3 (4 float4 chunks, coalesced)
  float s[16];
#pragma unroll
  for (int j = 0; j < 4; ++j) {
    float4 v = *reinterpret_cast<const float4*>(
        &emb[(size_t)b * D_ + lane * 4 + j * 256]);
    s[j * 4 + 0] = v.x; s[j * 4 + 1] = v.y;
    s[j * 4 + 2] = v.z; s[j * 4 + 3] = v.w;
  }
  float gm[16], bt[16];
#pragma unroll
  for (int j = 0; j < 4; ++j) {
    float4 g = *reinterpret_cast<const float4*>(&gamma[lane * 4 + j * 256]);
    float4 bb = *reinterpret_cast<const float4*>(&beta[lane * 4 + j * 256]);
    gm[j * 4 + 0] = g.x; gm[j * 4 + 1] = g.y;
    gm[j * 4 + 2] = g.z; gm[j * 4 + 3] = g.w;
    bt[j * 4 + 0] = bb.x; bt[j * 4 + 1] = bb.y;
    bt[j * 4 + 2] = bb.z; bt[j * 4 + 3] = bb.w;
  }

  // double-buffered gather: nxt holds row f's embedding (used at end of iter f)
  float4 nxt[4];
  {
    int feat = feats[b * F_ + 0];
    const float* row = tables + ((size_t)0 * V_ + feat) * D_;
#pragma unroll
    for (int j = 0; j < 4; ++j)
      nxt[j] = *reinterpret_cast<const float4*>(&row[lane * 4 + j * 256]);
  }

  for (int f = 0; f < F_; ++f) {
    float sum = 0.0f, ssq = 0.0f;
#pragma unroll
    for (int j = 0; j < 16; ++j) {
      sum += s[j];
      ssq += s[j] * s[j];
    }
#pragma unroll
    for (int off = 32; off > 0; off >>= 1) {
      sum += __shfl_xor(sum, off, 64);
      ssq += __shfl_xor(ssq, off, 64);
    }
    const float mu = sum * (1.0f / D_);
    const float var = ssq * (1.0f / D_) - mu * mu;
    const float rstd = rsqrtf(var + 1e-5f);

    __hip_bfloat16* Hrow = H + (size_t)f * (B_ * D_) + (size_t)b * D_;
#pragma unroll
    for (int j = 0; j < 4; ++j) {
      __hip_bfloat16 hb[4];
#pragma unroll
      for (int q = 0; q < 4; ++q) {
        float x = (s[j * 4 + q] - mu) * rstd * gm[j * 4 + q] + bt[j * 4 + q];
        hb[q] = __float2bfloat16(gelu_fast(x));
      }
      *reinterpret_cast<uint2*>(&Hrow[lane * 4 + j * 256]) =
          *reinterpret_cast<const uint2*>(hb);
    }

    if (f < F_ - 1) {
      // consume nxt (row f), then prefetch row f+1
      float4 cur[4];
#pragma unroll
      for (int j = 0; j < 4; ++j) cur[j] = nxt[j];
      if (f < F_ - 2) {
        int feat = feats[b * F_ + f + 1];
        const float* row = tables + ((size_t)(f + 1) * V_ + feat) * D_;
#pragma unroll
        for (int j = 0; j < 4; ++j)
          nxt[j] = *reinterpret_cast<const float4*>(&row[lane * 4 + j * 256]);
      }
#pragma unroll
      for (int j = 0; j < 4; ++j) {
        s[j * 4 + 0] += cur[j].x; s[j * 4 + 1] += cur[j].y;
        s[j * 4 + 2] += cur[j].z; s[j * 4 + 3] += cur[j].w;
      }
    }
  }
}

// ---------------------------------------------------------------------------
// Kernel 2: 256x256 8-phase GEMM (R3-exact, best measured), BK=64, 8 waves
// (2Mx4N), dbuf LDS, pre-swizzled global source, one raw s_barrier per phase,
// counted vmcnt(6) at PH4/PH8 only.
// ---------------------------------------------------------------------------
#define AOFF 0
#define BOFF 32768

#define STAGE(OPB, GB, DBUF, HALF, KT)                                        \
  do {                                                                        \
    const ushort* _g = (GB) + (size_t)(HALF) * (128 * D_) + (size_t)(KT) * 64;\
    ushort* _l = &lds[(OPB) + ((DBUF)*2 + (HALF)) * 8192 + w * 512];          \
    gload_lds16(_g, _l);                                                      \
    gload_lds16(_g + 64 * D_, _l + 4096);                                     \
  } while (0)

#define LD_A(DST, LBASE, FIOFF)                                               \
  _Pragma("unroll") for (int _fj = 0; _fj < 4; ++_fj)                         \
  _Pragma("unroll") for (int _ks = 0; _ks < 2; ++_ks)                         \
      DST[_fj][_ks] = *reinterpret_cast<const bf16x8*>(                       \
          (LBASE) + ((((FIOFF) + _fj) * 2 + _ks) * 512));

#define LD_B(DST, LBASE, NFOFF)                                               \
  _Pragma("unroll") for (int _fn = 0; _fn < 2; ++_fn)                         \
  _Pragma("unroll") for (int _ks = 0; _ks < 2; ++_ks)                         \
      DST[_fn][_ks] = *reinterpret_cast<const bf16x8*>(                       \
          (LBASE) + ((((NFOFF) + _fn) * 2 + _ks) * 512));

#define Q_MFMA(AF, BF, R0, C0)                                                \
  do {                                                                        \
    __builtin_amdgcn_s_setprio(1);                                            \
    _Pragma("unroll") for (int _fj = 0; _fj < 4; ++_fj)                       \
    _Pragma("unroll") for (int _fn = 0; _fn < 2; ++_fn)                       \
    _Pragma("unroll") for (int _ks = 0; _ks < 2; ++_ks)                       \
        acc[(R0) + _fj][(C0) + _fn] =                                         \
            __builtin_amdgcn_mfma_f32_16x16x32_bf16(                          \
                AF[_fj][_ks], BF[_fn][_ks], acc[(R0) + _fj][(C0) + _fn],      \
                0, 0, 0);                                                     \
    __builtin_amdgcn_s_setprio(0);                                            \
  } while (0)

#define PHB                                                                   \
  do {                                                                        \
    asm volatile("" ::: "memory");                                            \
    __builtin_amdgcn_s_barrier();                                             \
    asm volatile("" ::: "memory");                                            \
  } while (0)

#define WAITV6 asm volatile("s_waitcnt vmcnt(6)" ::: "memory")
#define WAITV0 asm volatile("s_waitcnt vmcnt(0)" ::: "memory")

__global__ __launch_bounds__(512, 2) void gemm_hw(
    const ushort* __restrict__ H,    // (F, B, D) bf16
    const ushort* __restrict__ Wt,   // (F, VP, D) bf16
    const float* __restrict__ bias,  // (F, V)
    float* __restrict__ out) {       // (B, F, V)
  __shared__ ushort lds[65536];  // 128 KiB

  // bijective XCD swizzle: nwg=512, 512%8==0
  const int bid = blockIdx.x;
  const int swz = (bid & 7) * 64 + (bid >> 3);
  const int f = swz >> 6;
  const int r = swz & 63;
  const int mt = r >> 2, nt = r & 3;

  const int t = threadIdx.x;
  const int w = t >> 6, l = t & 63;
  const int wm = w >> 2;   // 0..1 (M)
  const int wn = w & 3;    // 0..3 (N)

  const ushort* Hf = H + (size_t)f * (B_ * D_);
  const ushort* Wf = Wt + (size_t)f * (VP * D_);

  // staging global source (pre-swizzled so linear LDS write = swizzled layout)
  const int srow = ((w >> 1) << 4) + (l >> 2);
  const int skx = ((w & 1) << 5) + ((((l & 3) << 3)) ^ (((l >> 5) & 1) << 4));
  const ushort* gA = Hf + (size_t)(mt * 256 + srow) * D_ + skx;
  const ushort* gB = Wf + (size_t)(nt * 256 + srow) * D_ + skx;

  // ds_read per-lane offset (ushorts): same swizzle on read side
  const int laneu =
      ((l & 15) << 5) + (((((l >> 4) << 4)) ^ (((l >> 3) & 1) << 5)) >> 1);
  const ushort* lA[2] = {&lds[(0 * 2 + wm) * 8192 + laneu],
                         &lds[(1 * 2 + wm) * 8192 + laneu]};
  const ushort* lB[2] = {
      &lds[BOFF + (0 * 2 + (wn >> 1)) * 8192 + (wn & 1) * 4096 + laneu],
      &lds[BOFF + (1 * 2 + (wn >> 1)) * 8192 + (wn & 1) * 4096 + laneu]};

  bf16x8 a0[4][2], a1[4][2], b0[2][2], b1[2][2];
  f32x4 acc[8][4] = {};

  // prologue: T0 full + T1 {A0,A1,B0}; B1(T1) staged at PH1 of iter 0.
  STAGE(AOFF, gA, 0, 0, 0);
  STAGE(AOFF, gA, 0, 1, 0);
  STAGE(BOFF, gB, 0, 0, 0);
  STAGE(BOFF, gB, 0, 1, 0);
  STAGE(AOFF, gA, 1, 0, 1);
  STAGE(AOFF, gA, 1, 1, 1);
  STAGE(BOFF, gB, 1, 0, 1);
  WAITV6;  // 14 issued, keep 6 -> drains exactly T0's 8 loads
  PHB;

#pragma unroll 1
  for (int i = 0; i < 8; ++i) {
    const int t1 = 2 * i + 1, t2 = 2 * i + 2, t3 = 2 * i + 3;
    const bool more = (i < 7);
    // ---- PH1: read a0,b0(T0); stage B1(T1)
    LD_A(a0, lA[0], 0);
    LD_B(b0, lB[0], 0);
    STAGE(BOFF, gB, 1, 1, t1);
    PHB;
    Q_MFMA(a0, b0, 0, 0);
    // ---- PH2: read a1(T0); stage A0(T2)
    LD_A(a1, lA[0], 4);
    if (more) STAGE(AOFF, gA, 0, 0, t2);
    PHB;
    Q_MFMA(a1, b0, 4, 0);
    // ---- PH3: read b1(T0); stage A1(T2)
    LD_B(b1, lB[0], 2);
    if (more) STAGE(AOFF, gA, 0, 1, t2);
    PHB;
    Q_MFMA(a0, b1, 0, 2);
    // ---- PH4: stage B0(T2); counted wait (T1 fully landed)
    if (more) STAGE(BOFF, gB, 0, 0, t2);
    if (more) { WAITV6; } else { WAITV0; }
    PHB;
    Q_MFMA(a1, b1, 4, 2);
    // ---- PH5: read a0,b0(T1); stage B1(T2)
    LD_A(a0, lA[1], 0);
    LD_B(b0, lB[1], 0);
    if (more) STAGE(BOFF, gB, 0, 1, t2);
    PHB;
    Q_MFMA(a0, b0, 0, 0);
    // ---- PH6: read a1(T1); stage A0(T3)
    LD_A(a1, lA[1], 4);
    if (more) STAGE(AOFF, gA, 1, 0, t3);
    PHB;
    Q_MFMA(a1, b0, 4, 0);
    // ---- PH7: read b1(T1); stage A1(T3)
    LD_B(b1, lB[1], 2);
    if (more) STAGE(AOFF, gA, 1, 1, t3);
    PHB;
    Q_MFMA(a0, b1, 0, 2);
    // ---- PH8: stage B0(T3); counted wait (T2 fully landed)
    if (more) {
      STAGE(BOFF, gB, 1, 0, t3);
      WAITV6;
    }
    PHB;
    Q_MFMA(a1, b1, 4, 2);
  }

  // epilogue: C layout col = lane&15, row = (lane>>4)*4 + q
  const float* bp = bias + f * V_;
  const int orow0 = mt * 256 + wm * 128 + ((l >> 4) << 2);
  const int ocol0 = nt * 256 + wn * 64 + (l & 15);
#pragma unroll
  for (int fi = 0; fi < 8; ++fi) {
#pragma unroll
    for (int fn = 0; fn < 4; ++fn) {
      int col = ocol0 + fn * 16;
      if (col < V_) {
        float bb = bp[col];
        int row = orow0 + fi * 16;
        float* op = out + (size_t)row * (F_ * V_) + (size_t)f * V_ + col;
#pragma unroll
        for (int q = 0; q < 4; ++q)
          op[(size_t)q * (F_ * V_)] = acc[fi][fn][q] + bb;
      }
    }
  }
}

// ---------------------------------------------------------------------------
extern "C" void kernel_launch(void* const* d_in, const int* in_sizes, int n_in,
                              void* d_out, int out_size, void* d_ws,
                              size_t ws_size, hipStream_t stream) {
  const float* emb = (const float*)d_in[0];     // (B, D)
  const int* feats = (const int*)d_in[1];       // (B, F)
  const float* tables = (const float*)d_in[2];  // (F, V, D)
  const float* gamma = (const float*)d_in[3];   // (D,)
  const float* beta = (const float*)d_in[4];    // (D,)
  const float* W = (const float*)d_in[5];       // (F, D, V)
  const float* bias = (const float*)d_in[6];    // (F, V)
  float* out = (float*)d_out;                   // (B, F, V)

  char* ws = (char*)d_ws;
  __hip_bfloat16* Hbuf = (__hip_bfloat16*)ws;  // F*B*D*2 = 64 MiB
  __hip_bfloat16* Wtbuf =
      (__hip_bfloat16*)(ws + (size_t)F_ * B_ * D_ * 2);  // F*VP*D*2 = 16 MiB

  transpose_w<<<dim3(2048), dim3(256), 0, stream>>>(W, Wtbuf);
  fuse_h<<<dim3(1024), dim3(256), 0, stream>>>(emb, feats, tables, gamma,
                                               beta, Hbuf);
  gemm_hw<<<dim3((B_ / 256) * (VP / 256) * F_), dim3(512), 0, stream>>>(
      (const ushort*)Hbuf, (const ushort*)Wtbuf, bias, out);
}